// Round 2
// baseline (675.018 us; speedup 1.0000x reference)
//
#include <hip/hip_runtime.h>
#include <hip/hip_bf16.h>

// ---------------- transposed-weight workspace layout (floats) ----------------
#define OFF_MSG1T 0        // [67][32] = 2144
#define OFF_MSG2T 2144     // [32][32] = 1024
#define OFF_GR    3168     // [64][32] = 2048  (k<32: w_ih rows 0..31 ; k>=32: w_hh rows 0..31)
#define OFF_GZ    5216     // [64][32] = 2048  (rows 32..63)
#define OFF_GN    7264     // [64][32] = 2048  (rows 64..95)
#define OFF_BR    9312     // [32] b_ih+b_hh (r)
#define OFF_BZ    9344     // [32] (z)
#define OFF_WC    9376     // [32][32] folded (Wo@Wv)^T
#define OFF_BC    10400    // [32] Wo@bv+bo
#define OFF_E1    10432    // [34][32]
#define OFF_E2    11520    // [32][32]
#define OFF_C1    12544    // [32][32]

#define BLK 128
#define EDGE_BLOCKS 7815   // multiple of 3; 7815*128 = 1000320 >= E
#define COPY_BLOCKS 2605   // EDGE_BLOCKS/3
#define GRID (COPY_BLOCKS * 4)

__device__ __forceinline__ float sigf(float v) { return 1.0f / (1.0f + __expf(-v)); }
__device__ __forceinline__ float tanhf_fast(float v) {
    float a = fabsf(v);
    float t = __expf(-2.0f * a);
    float r = (1.0f - t) / (1.0f + t);
    return v < 0.0f ? -r : r;
}

// pack two f32 -> (bf16lo | bf16hi<<16), RNE
__device__ __forceinline__ unsigned pk(float a, float b) {
    union { __hip_bfloat162 h; unsigned u; } cv;
    cv.h = __float22bfloat162_rn(make_float2(a, b));
    return cv.u;
}
__device__ __forceinline__ float uplo(unsigned u) { return __uint_as_float(u << 16); }
__device__ __forceinline__ float uphi(unsigned u) { return __uint_as_float(u & 0xffff0000u); }

// acc[j] += x_{2p} * WT[2(p-P0)][j] + x_{2p+1} * WT[2(p-P0)+1][j]
// x packed bf16 in own LDS column (stride BLK u32); weights wave-uniform fp32 -> s_load
template <int P0, int P1>
__device__ __forceinline__ void passP(float* acc, const float* __restrict__ WT,
                                      const unsigned* xcol) {
#pragma unroll 2
    for (int p = P0; p < P1; ++p) {
        unsigned u = xcol[p * BLK];
        float xa = uplo(u), xb = uphi(u);
        const float* w = &WT[(2 * (p - P0)) * 32];
#pragma unroll
        for (int j = 0; j < 32; ++j) acc[j] = fmaf(xa, w[j], acc[j]);
#pragma unroll
        for (int j = 0; j < 32; ++j) acc[j] = fmaf(xb, w[32 + j], acc[j]);
    }
}

__global__ void winner_k(const int* __restrict__ dst_ids, int* __restrict__ winner, int E) {
    int e = blockIdx.x * 256 + threadIdx.x;
    if (e < E) atomicMax(winner + dst_ids[e], e + 1);
}

__global__ void prep_k(const float* __restrict__ msg_W1, const float* __restrict__ msg_W2,
                       const float* __restrict__ w_ih, const float* __restrict__ b_ih,
                       const float* __restrict__ w_hh, const float* __restrict__ b_hh,
                       const float* __restrict__ Wv, const float* __restrict__ bv,
                       const float* __restrict__ Wo, const float* __restrict__ bo,
                       const float* __restrict__ emb_W1, const float* __restrict__ emb_W2,
                       const float* __restrict__ cls_W1, float* __restrict__ WS) {
    int t = threadIdx.x;  // 256 threads, 1 block
    for (int i = t; i < 67 * 32; i += 256) { int k = i >> 5, j = i & 31; WS[OFF_MSG1T + i] = msg_W1[j * 67 + k]; }
    for (int i = t; i < 1024; i += 256)    { int k = i >> 5, j = i & 31; WS[OFF_MSG2T + i] = msg_W2[j * 32 + k]; }
    for (int i = t; i < 2048; i += 256) {
        int k = i >> 5, j = i & 31;
        WS[OFF_GR + i] = (k < 32) ? w_ih[j * 32 + k]          : w_hh[j * 32 + (k - 32)];
        WS[OFF_GZ + i] = (k < 32) ? w_ih[(32 + j) * 32 + k]   : w_hh[(32 + j) * 32 + (k - 32)];
        WS[OFF_GN + i] = (k < 32) ? w_ih[(64 + j) * 32 + k]   : w_hh[(64 + j) * 32 + (k - 32)];
    }
    if (t < 32) {
        WS[OFF_BR + t] = b_ih[t] + b_hh[t];
        WS[OFF_BZ + t] = b_ih[32 + t] + b_hh[32 + t];
    }
    for (int i = t; i < 1024; i += 256) {  // WcT[k][j] = sum_o Wo[j][o]*Wv[o][k]
        int k = i >> 5, j = i & 31;
        float a = 0.0f;
        for (int o = 0; o < 32; ++o) a += Wo[j * 32 + o] * Wv[o * 32 + k];
        WS[OFF_WC + i] = a;
    }
    if (t < 32) {
        float a = bo[t];
        for (int o = 0; o < 32; ++o) a += Wo[t * 32 + o] * bv[o];
        WS[OFF_BC + t] = a;
    }
    for (int i = t; i < 34 * 32; i += 256) { int k = i >> 5, j = i & 31; WS[OFF_E1 + i] = emb_W1[j * 34 + k]; }
    for (int i = t; i < 1024; i += 256)    { int k = i >> 5, j = i & 31; WS[OFF_E2 + i] = emb_W2[j * 32 + k]; }
    for (int i = t; i < 1024; i += 256)    { int k = i >> 5, j = i & 31; WS[OFF_C1 + i] = cls_W1[j * 32 + k]; }
}

__global__ __launch_bounds__(BLK, 4) void tgn_fused(
    const int* __restrict__ src_ids, const int* __restrict__ dst_ids,
    const float* __restrict__ edge_feat, const float* __restrict__ delta_t,
    const float* __restrict__ memory,
    const float* __restrict__ msg_b1, const float* __restrict__ msg_b2,
    const float* __restrict__ gru_b_ih, const float* __restrict__ gru_b_hh,
    const float* __restrict__ emb_b1, const float* __restrict__ emb_b2,
    const float* __restrict__ cls_b1, const float* __restrict__ cls_b2,
    const float* __restrict__ cls_W2,
    const float* __restrict__ WS, const int* __restrict__ winner,
    float* __restrict__ probs, float* __restrict__ out_mem, int E, int N) {
    // packed-bf16 activation columns: [32 packs][BLK threads] u32 = 16 KB
    __shared__ unsigned xs[32 * BLK];
    int bid = blockIdx.x, tid = threadIdx.x;
    int r4 = bid & 3;

    if (r4 == 3) {  // ---- copy worker: non-winner rows of memory -> out_mem ----
        int cw = bid >> 2;
        const float4* m4 = (const float4*)memory;
        float4* o4 = (float4*)out_mem;
        int total4 = N * 8;
        for (int i = cw * BLK + tid; i < total4; i += COPY_BLOCKS * BLK) {
            int row = i >> 3;
            if (winner[row] == 0) o4[i] = m4[i];
        }
        return;
    }

    // ---- edge worker: one edge per thread ----
    int wid = (bid >> 2) * 3 + r4;  // 0 .. EDGE_BLOCKS-1
    unsigned* xcol = &xs[tid];
    const float4* m4 = (const float4*)memory;

    for (int e = wid * BLK + tid; e < E; e += EDGE_BLOCKS * BLK) {
        int src = src_ids[e], dst = dst_ids[e];
        float2 ef = ((const float2*)edge_feat)[e];
        float dt = delta_t[e];
        bool win = (winner[dst] == e + 1);

        // stage x = [src_mem -> packs 0..15, dst_mem -> packs 16..31]
#pragma unroll
        for (int i = 0; i < 8; ++i) {
            float4 v = m4[(size_t)src * 8 + i];
            xcol[(2 * i + 0) * BLK] = pk(v.x, v.y);
            xcol[(2 * i + 1) * BLK] = pk(v.z, v.w);
        }
#pragma unroll
        for (int i = 0; i < 8; ++i) {
            float4 v = m4[(size_t)dst * 8 + i];
            xcol[(16 + 2 * i + 0) * BLK] = pk(v.x, v.y);
            xcol[(16 + 2 * i + 1) * BLK] = pk(v.z, v.w);
        }

        float acc[32];
        // ---- msg layer 1: relu(W1 @ [sm,dm,ef,dt] + b1) ----
#pragma unroll
        for (int j = 0; j < 32; ++j) acc[j] = msg_b1[j];
        passP<0, 32>(acc, WS + OFF_MSG1T, xcol);
        {
            const float* wa = WS + OFF_MSG1T + 64 * 32;
            const float* wb = WS + OFF_MSG1T + 65 * 32;
            const float* wc = WS + OFF_MSG1T + 66 * 32;
#pragma unroll
            for (int j = 0; j < 32; ++j)
                acc[j] = fmaf(ef.x, wa[j], fmaf(ef.y, wb[j], fmaf(dt, wc[j], acc[j])));
        }
#pragma unroll
        for (int p = 0; p < 16; ++p)   // h -> packs 0..15
            xcol[p * BLK] = pk(fmaxf(acc[2 * p], 0.0f), fmaxf(acc[2 * p + 1], 0.0f));

        // ---- msg layer 2 ----
#pragma unroll
        for (int j = 0; j < 32; ++j) acc[j] = msg_b2[j];
        passP<0, 16>(acc, WS + OFF_MSG2T, xcol);
#pragma unroll
        for (int p = 0; p < 16; ++p)   // msg -> packs 0..15
            xcol[p * BLK] = pk(acc[2 * p], acc[2 * p + 1]);

        // ---- GRU z over [msg, dm] ----
        float z_[32];
#pragma unroll
        for (int j = 0; j < 32; ++j) z_[j] = WS[OFF_BZ + j];
        passP<0, 32>(z_, WS + OFF_GZ, xcol);
#pragma unroll
        for (int j = 0; j < 32; ++j) z_[j] = sigf(z_[j]);
        // ---- h_n = b_hh_n + Whh_n @ dm ----
        float hn[32];
#pragma unroll
        for (int j = 0; j < 32; ++j) hn[j] = gru_b_hh[64 + j];
        passP<16, 32>(hn, WS + OFF_GN + 32 * 32, xcol);
        // ---- r ----
        float r_[32];
#pragma unroll
        for (int j = 0; j < 32; ++j) r_[j] = WS[OFF_BR + j];
        passP<0, 32>(r_, WS + OFF_GR, xcol);
        // ---- n pre-act = b_ih_n + r*h_n + Wih_n @ msg ----
#pragma unroll
        for (int j = 0; j < 32; ++j) acc[j] = fmaf(sigf(r_[j]), hn[j], gru_b_ih[64 + j]);
        passP<0, 16>(acc, WS + OFF_GN, xcol);
        // ---- blend + winner write ----
        float u_[32];
#pragma unroll
        for (int p = 0; p < 16; ++p) {
            unsigned ud = xcol[(16 + p) * BLK];
            float d0 = uplo(ud), d1 = uphi(ud);
            float n0 = tanhf_fast(acc[2 * p]), n1 = tanhf_fast(acc[2 * p + 1]);
            u_[2 * p]     = n0 + z_[2 * p]     * (d0 - n0);
            u_[2 * p + 1] = n1 + z_[2 * p + 1] * (d1 - n1);
        }
        if (win) {
            float4* orow = (float4*)(out_mem + (size_t)dst * 32);
#pragma unroll
            for (int i = 0; i < 8; ++i)
                orow[i] = make_float4(u_[4 * i], u_[4 * i + 1], u_[4 * i + 2], u_[4 * i + 3]);
        }

        // ---- attn (folded 32x32) over dm ----
#pragma unroll
        for (int j = 0; j < 32; ++j) acc[j] = WS[OFF_BC + j];
        passP<16, 32>(acc, WS + OFF_WC, xcol);
#pragma unroll
        for (int p = 0; p < 16; ++p)   // at -> packs 0..15
            xcol[p * BLK] = pk(acc[2 * p], acc[2 * p + 1]);

        // ---- emb layer 1: relu(E1 @ [at, ef]) ----
#pragma unroll
        for (int j = 0; j < 32; ++j) acc[j] = emb_b1[j];
        passP<0, 16>(acc, WS + OFF_E1, xcol);
        {
            const float* wa = WS + OFF_E1 + 32 * 32;
            const float* wb = WS + OFF_E1 + 33 * 32;
#pragma unroll
            for (int j = 0; j < 32; ++j) acc[j] = fmaf(ef.x, wa[j], fmaf(ef.y, wb[j], acc[j]));
        }
#pragma unroll
        for (int p = 0; p < 16; ++p)
            xcol[p * BLK] = pk(fmaxf(acc[2 * p], 0.0f), fmaxf(acc[2 * p + 1], 0.0f));

        // ---- emb layer 2 ----
#pragma unroll
        for (int j = 0; j < 32; ++j) acc[j] = emb_b2[j];
        passP<0, 16>(acc, WS + OFF_E2, xcol);
#pragma unroll
        for (int p = 0; p < 16; ++p)
            xcol[p * BLK] = pk(acc[2 * p], acc[2 * p + 1]);

        // ---- cls layer 1 (regs) + logit ----
#pragma unroll
        for (int j = 0; j < 32; ++j) acc[j] = cls_b1[j];
        passP<0, 16>(acc, WS + OFF_C1, xcol);
        float lg = cls_b2[0];
#pragma unroll
        for (int k = 0; k < 32; ++k) lg = fmaf(fmaxf(acc[k], 0.0f), cls_W2[k], lg);
        probs[e] = sigf(lg);
    }
}

extern "C" void kernel_launch(void* const* d_in, const int* in_sizes, int n_in,
                              void* d_out, int out_size, void* d_ws, size_t ws_size,
                              hipStream_t stream) {
    const int*   src_ids   = (const int*)d_in[0];
    const int*   dst_ids   = (const int*)d_in[1];
    const float* edge_feat = (const float*)d_in[2];
    const float* delta_t   = (const float*)d_in[3];
    const float* memory    = (const float*)d_in[4];
    const float* msg_W1 = (const float*)d_in[5],  *msg_b1 = (const float*)d_in[6];
    const float* msg_W2 = (const float*)d_in[7],  *msg_b2 = (const float*)d_in[8];
    const float* w_ih   = (const float*)d_in[9],  *b_ih   = (const float*)d_in[10];
    const float* w_hh   = (const float*)d_in[11], *b_hh   = (const float*)d_in[12];
    const float* Wv     = (const float*)d_in[13], *bv     = (const float*)d_in[14];
    const float* Wo     = (const float*)d_in[15], *bo     = (const float*)d_in[16];
    const float* emb_W1 = (const float*)d_in[17], *emb_b1 = (const float*)d_in[18];
    const float* emb_W2 = (const float*)d_in[19], *emb_b2 = (const float*)d_in[20];
    const float* cls_W1 = (const float*)d_in[21], *cls_b1 = (const float*)d_in[22];
    const float* cls_W2 = (const float*)d_in[23], *cls_b2 = (const float*)d_in[24];

    int E = in_sizes[0];
    int N = in_sizes[4] / 32;

    int*   winner = (int*)d_ws;
    float* WS     = (float*)((char*)d_ws + (size_t)N * sizeof(int));
    float* probs  = (float*)d_out;
    float* outmem = probs + E;

    hipMemsetAsync(winner, 0, (size_t)N * sizeof(int), stream);
    winner_k<<<(E + 255) / 256, 256, 0, stream>>>(dst_ids, winner, E);
    prep_k<<<1, 256, 0, stream>>>(msg_W1, msg_W2, w_ih, b_ih, w_hh, b_hh,
                                  Wv, bv, Wo, bo, emb_W1, emb_W2, cls_W1, WS);
    tgn_fused<<<GRID, BLK, 0, stream>>>(
        src_ids, dst_ids, edge_feat, delta_t, memory,
        msg_b1, msg_b2, b_ih, b_hh, emb_b1, emb_b2, cls_b1, cls_b2, cls_W2,
        WS, winner, probs, outmem, E, N);
}

// Round 3
// 363.360 us; speedup vs baseline: 1.8577x; 1.8577x over previous
//
#include <hip/hip_runtime.h>
#include <hip/hip_bf16.h>

typedef float  f32x4  __attribute__((ext_vector_type(4)));
typedef short  bf16x8 __attribute__((ext_vector_type(8)));

#define NFRAG   26
#define TB_F32  512                            // 16 tables x 32 f32
#define FRG_U16 (NFRAG*512)                    // 26 frags x 64 lanes x 8 bf16
#define SHARE_BYTES (TB_F32*4 + FRG_U16*2)     // 28672 B staged to LDS
#define SHARE_U4 (SHARE_BYTES/16)              // 1792 uint4
#define XPK_STRIDE 20                          // u32 stride per edge row (bank spread)
#define SM_F32 (SHARE_BYTES/4 + 4*16*XPK_STRIDE)  // 8448 floats = 33792 B
#define WC_OFF 7168                            // WC scratch offset in WS floats

#define BLK 256
#define GRID 1024
#define COPY_BLOCKS 256
#define EDGE_WAVES 3072

#define MFMA(a,b,c) __builtin_amdgcn_mfma_f32_16x16x32_bf16(a,b,c,0,0,0)

__device__ __forceinline__ float sigf(float v) { return 1.0f / (1.0f + __expf(-v)); }
__device__ __forceinline__ float tanhf_fast(float v) {
    float a = fabsf(v);
    float t = __expf(-2.0f * a);
    float r = (1.0f - t) / (1.0f + t);
    return v < 0.0f ? -r : r;
}
__device__ __forceinline__ unsigned pk(float a, float b) {   // bf16(a) lo | bf16(b) hi
    union { __hip_bfloat162 h; unsigned u; } c;
    c.h = __float22bfloat162_rn(make_float2(a, b));
    return c.u;
}

union FragU { uint4 u4; bf16x8 s8; unsigned u[4]; };

__device__ __forceinline__ bf16x8 ldfrag(const unsigned short* frg, int idx_u16) {
    FragU c; c.u4 = *(const uint4*)(frg + idx_u16); return c.s8;
}
__device__ __forceinline__ f32x4 tbl(const float* tb, int idx_f32) {
    return *(const f32x4*)(tb + idx_f32);
}
// D(2 tiles, f32) -> next layer's B fragment via per-wave LDS bounce.
// write: tile jt, regs i -> j = jt*16+4g+i ; pairs -> u32 k2 = jt*8+2g+{0,1}
// read : k = 8g..8g+7 -> u32 k2 = 4g..4g+3
__device__ __forceinline__ bf16x8 relayout(f32x4 h0, f32x4 h1, unsigned* xw, int eI, int g) {
    *(uint2*)(xw + eI * XPK_STRIDE + 2 * g)     = make_uint2(pk(h0[0], h0[1]), pk(h0[2], h0[3]));
    *(uint2*)(xw + eI * XPK_STRIDE + 8 + 2 * g) = make_uint2(pk(h1[0], h1[1]), pk(h1[2], h1[3]));
    FragU c; c.u4 = *(const uint4*)(xw + eI * XPK_STRIDE + 4 * g);
    return c.s8;
}

__global__ void winner_k(const int* __restrict__ dst_ids, int* __restrict__ winner, int E) {
    int e = blockIdx.x * 256 + threadIdx.x;
    if (e < E) atomicMax(winner + dst_ids[e], e + 1);
}

__global__ void prep_k(const float* __restrict__ msg_W1, const float* __restrict__ msg_b1,
                       const float* __restrict__ msg_W2, const float* __restrict__ msg_b2,
                       const float* __restrict__ w_ih, const float* __restrict__ b_ih,
                       const float* __restrict__ w_hh, const float* __restrict__ b_hh,
                       const float* __restrict__ Wv, const float* __restrict__ bv,
                       const float* __restrict__ Wo, const float* __restrict__ bo,
                       const float* __restrict__ emb_W1, const float* __restrict__ emb_b1,
                       const float* __restrict__ emb_W2, const float* __restrict__ emb_b2,
                       const float* __restrict__ cls_W1, const float* __restrict__ cls_b1,
                       const float* __restrict__ cls_W2, float* __restrict__ WSf) {
    int t = threadIdx.x;  // one block, 256 threads
    float* tb = WSf;
    unsigned short* frg = (unsigned short*)(WSf + TB_F32);
    float* WC = WSf + WC_OFF;  // [32][32] folded Wo@Wv
    if (t < 32) {
        int j = t;
        tb[0*32+j]  = msg_b1[j];
        tb[1*32+j]  = msg_W1[j*67+64];
        tb[2*32+j]  = msg_W1[j*67+65];
        tb[3*32+j]  = msg_W1[j*67+66];
        tb[4*32+j]  = msg_b2[j];
        tb[5*32+j]  = b_ih[32+j] + b_hh[32+j];     // z bias
        tb[6*32+j]  = b_ih[j] + b_hh[j];           // r bias
        tb[7*32+j]  = b_hh[64+j];                  // h_n bias
        tb[8*32+j]  = b_ih[64+j];                  // i_n bias
        float a = bo[j];
        for (int o = 0; o < 32; ++o) a += Wo[j*32+o] * bv[o];
        tb[9*32+j]  = a;                           // folded attn bias
        tb[10*32+j] = emb_b1[j];
        tb[11*32+j] = emb_W1[j*34+32];
        tb[12*32+j] = emb_W1[j*34+33];
        tb[13*32+j] = emb_b2[j];
        tb[14*32+j] = cls_b1[j];
        tb[15*32+j] = cls_W2[j];
    }
    for (int i = t; i < 1024; i += 256) {
        int j = i >> 5, k = i & 31;
        float a = 0.0f;
        for (int o = 0; o < 32; ++o) a += Wo[j*32+o] * Wv[o*32+k];
        WC[i] = a;
    }
    __syncthreads();
    // A-fragment pack: frag f, lane l, elem i -> W[j0 + (l&15)][k0 + 8*(l>>4) + i]
    for (int idx = t; idx < NFRAG * 512; idx += 256) {
        int f = idx >> 9, l = (idx >> 3) & 63, i = idx & 7;
        int r = l & 15, kb = ((l >> 4) << 3) + i;
        const float* P; int j0 = 0, k0 = 0, ld = 32;
        switch (f) {
            case 0:  P = msg_W1; j0 = 0;  k0 = 0;  ld = 67; break;
            case 1:  P = msg_W1; j0 = 0;  k0 = 32; ld = 67; break;
            case 2:  P = msg_W1; j0 = 16; k0 = 0;  ld = 67; break;
            case 3:  P = msg_W1; j0 = 16; k0 = 32; ld = 67; break;
            case 4:  P = msg_W2; j0 = 0;  break;
            case 5:  P = msg_W2; j0 = 16; break;
            case 6:  P = w_ih;   j0 = 32; break;   // z ih jt0
            case 7:  P = w_hh;   j0 = 32; break;   // z hh jt0
            case 8:  P = w_ih;   j0 = 48; break;
            case 9:  P = w_hh;   j0 = 48; break;
            case 10: P = w_ih;   j0 = 0;  break;   // r
            case 11: P = w_hh;   j0 = 0;  break;
            case 12: P = w_ih;   j0 = 16; break;
            case 13: P = w_hh;   j0 = 16; break;
            case 14: P = w_hh;   j0 = 64; break;   // n hh
            case 15: P = w_hh;   j0 = 80; break;
            case 16: P = w_ih;   j0 = 64; break;   // n ih
            case 17: P = w_ih;   j0 = 80; break;
            case 18: P = WC;     j0 = 0;  break;   // folded attn
            case 19: P = WC;     j0 = 16; break;
            case 20: P = emb_W1; j0 = 0;  ld = 34; break;
            case 21: P = emb_W1; j0 = 16; ld = 34; break;
            case 22: P = emb_W2; j0 = 0;  break;
            case 23: P = emb_W2; j0 = 16; break;
            case 24: P = cls_W1; j0 = 0;  break;
            default: P = cls_W1; j0 = 16; break;
        }
        __hip_bfloat16 hv = __float2bfloat16(P[(j0 + r) * ld + k0 + kb]);
        frg[idx] = *(unsigned short*)&hv;
    }
}

__global__ __launch_bounds__(BLK, 3) void tgn_mfma(
    const int* __restrict__ src_ids, const int* __restrict__ dst_ids,
    const float* __restrict__ edge_feat, const float* __restrict__ delta_t,
    const float* __restrict__ memory, const float* __restrict__ cls_b2,
    const float* __restrict__ WSf, const int* __restrict__ winner,
    float* __restrict__ probs, float* __restrict__ out_mem,
    int E, int N, int ngrp) {
    __shared__ float smem[SM_F32];
    int bid = blockIdx.x, tid = threadIdx.x;
    int r4 = bid & 3;

    if (r4 == 3) {  // ---- copy worker: non-winner rows memory -> out_mem ----
        int cw = bid >> 2;
        const float4* m4 = (const float4*)memory;
        float4* o4 = (float4*)out_mem;
        long total4 = (long)N * 8;
        for (long i = cw * BLK + tid; i < total4; i += (long)COPY_BLOCKS * BLK) {
            int row = (int)(i >> 3);
            if (winner[row] == 0) o4[i] = m4[i];
        }
        return;
    }

    {   // stage tables + A-fragments (block-shared, read-only afterwards)
        const uint4* s = (const uint4*)WSf;
        uint4* d = (uint4*)smem;
        for (int i = tid; i < SHARE_U4; i += BLK) d[i] = s[i];
    }
    __syncthreads();
    const float* tb = smem;
    const unsigned short* frg = (const unsigned short*)(smem + TB_F32);
    int wv = tid >> 6, lane = tid & 63;
    int eI = lane & 15, g = lane >> 4;
    unsigned* xw = (unsigned*)(smem + SHARE_BYTES / 4) + wv * (16 * XPK_STRIDE);
    int ewid = ((bid >> 2) * 3 + r4) * 4 + wv;
    float clsb2 = cls_b2[0];

    for (int grp = ewid; grp < ngrp; grp += EDGE_WAVES) {
        int e = grp * 16 + eI; if (e >= E) e = E - 1;
        int ob = 0, tbo = 0;
        asm volatile("" : "+v"(ob), "+v"(tbo));  // block LICM of LDS frag/table reads
        int src = src_ids[e], dst = dst_ids[e];
        float2 ef = ((const float2*)edge_feat)[e];
        float dtv = delta_t[e];
        bool win = (winner[dst] == e + 1);
        const f32x4* sp = (const f32x4*)(memory + (size_t)src * 32);
        const f32x4* dp = (const f32x4*)(memory + (size_t)dst * 32);
        f32x4 sa = sp[2*g], sb = sp[2*g+1];
        f32x4 da = dp[2*g], db = dp[2*g+1];
        FragU Bs, Bd;
        Bs.u[0] = pk(sa[0], sa[1]); Bs.u[1] = pk(sa[2], sa[3]);
        Bs.u[2] = pk(sb[0], sb[1]); Bs.u[3] = pk(sb[2], sb[3]);
        Bd.u[0] = pk(da[0], da[1]); Bd.u[1] = pk(da[2], da[3]);
        Bd.u[2] = pk(db[0], db[1]); Bd.u[3] = pk(db[2], db[3]);
        f32x4 dmt[2];                 // dst mem in D layout (exact f32, L2-hot)
        dmt[0] = dp[g]; dmt[1] = dp[4 + g];

        // ---- msg1: relu(W1 @ [sm, dm, ef, dt] + b1) ----
        f32x4 h[2];
#pragma unroll
        for (int jt = 0; jt < 2; ++jt) {
            f32x4 b1v = tbl(tb, 0*32 + jt*16 + 4*g + tbo);
            f32x4 w64 = tbl(tb, 1*32 + jt*16 + 4*g + tbo);
            f32x4 w65 = tbl(tb, 2*32 + jt*16 + 4*g + tbo);
            f32x4 w66 = tbl(tb, 3*32 + jt*16 + 4*g + tbo);
            f32x4 c;
#pragma unroll
            for (int i = 0; i < 4; ++i)
                c[i] = b1v[i] + ef.x * w64[i] + ef.y * w65[i] + dtv * w66[i];
            c = MFMA(ldfrag(frg, (jt*2+1)*512 + lane*8 + ob), Bd.s8, c);
            c = MFMA(ldfrag(frg, (jt*2+0)*512 + lane*8 + ob), Bs.s8, c);
#pragma unroll
            for (int i = 0; i < 4; ++i) c[i] = fmaxf(c[i], 0.0f);
            h[jt] = c;
        }
        bf16x8 Bh = relayout(h[0], h[1], xw, eI, g);

        // ---- msg2 ----
        f32x4 m[2];
#pragma unroll
        for (int jt = 0; jt < 2; ++jt)
            m[jt] = MFMA(ldfrag(frg, (4+jt)*512 + lane*8 + ob), Bh,
                         tbl(tb, 4*32 + jt*16 + 4*g + tbo));
        bf16x8 Bm = relayout(m[0], m[1], xw, eI, g);

        // ---- GRU ----
        f32x4 zz[2], uu[2];
#pragma unroll
        for (int jt = 0; jt < 2; ++jt) {
            f32x4 c = tbl(tb, 5*32 + jt*16 + 4*g + tbo);
            c = MFMA(ldfrag(frg, (7+2*jt)*512 + lane*8 + ob), Bd.s8, c);
            c = MFMA(ldfrag(frg, (6+2*jt)*512 + lane*8 + ob), Bm, c);
#pragma unroll
            for (int i = 0; i < 4; ++i) c[i] = sigf(c[i]);
            zz[jt] = c;
        }
#pragma unroll
        for (int jt = 0; jt < 2; ++jt) {
            f32x4 c = tbl(tb, 6*32 + jt*16 + 4*g + tbo);       // r pre-act
            c = MFMA(ldfrag(frg, (11+2*jt)*512 + lane*8 + ob), Bd.s8, c);
            c = MFMA(ldfrag(frg, (10+2*jt)*512 + lane*8 + ob), Bm, c);
            f32x4 hn = tbl(tb, 7*32 + jt*16 + 4*g + tbo);      // h_n
            hn = MFMA(ldfrag(frg, (14+jt)*512 + lane*8 + ob), Bd.s8, hn);
            f32x4 bin = tbl(tb, 8*32 + jt*16 + 4*g + tbo);
            f32x4 npre;
#pragma unroll
            for (int i = 0; i < 4; ++i) npre[i] = fmaf(sigf(c[i]), hn[i], bin[i]);
            npre = MFMA(ldfrag(frg, (16+jt)*512 + lane*8 + ob), Bm, npre);
#pragma unroll
            for (int i = 0; i < 4; ++i) {
                float n = tanhf_fast(npre[i]);
                uu[jt][i] = n + zz[jt][i] * (dmt[jt][i] - n);
            }
        }
        if (win) {
            f32x4* orow = (f32x4*)(out_mem + (size_t)dst * 32);
            orow[g]     = uu[0];
            orow[4 + g] = uu[1];
        }

        // ---- attn (folded) -> emb1 -> emb2 -> cls ----
        f32x4 at[2];
#pragma unroll
        for (int jt = 0; jt < 2; ++jt)
            at[jt] = MFMA(ldfrag(frg, (18+jt)*512 + lane*8 + ob), Bd.s8,
                          tbl(tb, 9*32 + jt*16 + 4*g + tbo));
        bf16x8 Ba = relayout(at[0], at[1], xw, eI, g);
        f32x4 e1v[2];
#pragma unroll
        for (int jt = 0; jt < 2; ++jt) {
            f32x4 b  = tbl(tb, 10*32 + jt*16 + 4*g + tbo);
            f32x4 wa = tbl(tb, 11*32 + jt*16 + 4*g + tbo);
            f32x4 wb = tbl(tb, 12*32 + jt*16 + 4*g + tbo);
            f32x4 c;
#pragma unroll
            for (int i = 0; i < 4; ++i) c[i] = b[i] + ef.x * wa[i] + ef.y * wb[i];
            c = MFMA(ldfrag(frg, (20+jt)*512 + lane*8 + ob), Ba, c);
#pragma unroll
            for (int i = 0; i < 4; ++i) c[i] = fmaxf(c[i], 0.0f);
            e1v[jt] = c;
        }
        bf16x8 B1 = relayout(e1v[0], e1v[1], xw, eI, g);
        f32x4 e2v[2];
#pragma unroll
        for (int jt = 0; jt < 2; ++jt)
            e2v[jt] = MFMA(ldfrag(frg, (22+jt)*512 + lane*8 + ob), B1,
                           tbl(tb, 13*32 + jt*16 + 4*g + tbo));
        bf16x8 B2 = relayout(e2v[0], e2v[1], xw, eI, g);
        float part = 0.0f;
#pragma unroll
        for (int jt = 0; jt < 2; ++jt) {
            f32x4 c = MFMA(ldfrag(frg, (24+jt)*512 + lane*8 + ob), B2,
                           tbl(tb, 14*32 + jt*16 + 4*g + tbo));
            f32x4 w2 = tbl(tb, 15*32 + jt*16 + 4*g + tbo);
#pragma unroll
            for (int i = 0; i < 4; ++i) part = fmaf(fmaxf(c[i], 0.0f), w2[i], part);
        }
        part += __shfl_xor(part, 16);
        part += __shfl_xor(part, 32);
        if (lane < 16) {
            int ee = grp * 16 + eI;
            if (ee < E) probs[ee] = sigf(part + clsb2);
        }
    }
}

extern "C" void kernel_launch(void* const* d_in, const int* in_sizes, int n_in,
                              void* d_out, int out_size, void* d_ws, size_t ws_size,
                              hipStream_t stream) {
    const int*   src_ids   = (const int*)d_in[0];
    const int*   dst_ids   = (const int*)d_in[1];
    const float* edge_feat = (const float*)d_in[2];
    const float* delta_t   = (const float*)d_in[3];
    const float* memory    = (const float*)d_in[4];
    const float* msg_W1 = (const float*)d_in[5],  *msg_b1 = (const float*)d_in[6];
    const float* msg_W2 = (const float*)d_in[7],  *msg_b2 = (const float*)d_in[8];
    const float* w_ih   = (const float*)d_in[9],  *b_ih   = (const float*)d_in[10];
    const float* w_hh   = (const float*)d_in[11], *b_hh   = (const float*)d_in[12];
    const float* Wv     = (const float*)d_in[13], *bv     = (const float*)d_in[14];
    const float* Wo     = (const float*)d_in[15], *bo     = (const float*)d_in[16];
    const float* emb_W1 = (const float*)d_in[17], *emb_b1 = (const float*)d_in[18];
    const float* emb_W2 = (const float*)d_in[19], *emb_b2 = (const float*)d_in[20];
    const float* cls_W1 = (const float*)d_in[21], *cls_b1 = (const float*)d_in[22];
    const float* cls_W2 = (const float*)d_in[23], *cls_b2 = (const float*)d_in[24];

    int E = in_sizes[0];
    int N = in_sizes[4] / 32;
    int ngrp = (E + 15) / 16;

    int*   winner = (int*)d_ws;
    float* WSf    = (float*)((char*)d_ws + (size_t)N * sizeof(int));
    float* probs  = (float*)d_out;
    float* outmem = probs + E;

    hipMemsetAsync(winner, 0, (size_t)N * sizeof(int), stream);
    winner_k<<<(E + 255) / 256, 256, 0, stream>>>(dst_ids, winner, E);
    prep_k<<<1, 256, 0, stream>>>(msg_W1, msg_b1, msg_W2, msg_b2,
                                  w_ih, b_ih, w_hh, b_hh,
                                  Wv, bv, Wo, bo,
                                  emb_W1, emb_b1, emb_W2, emb_b2,
                                  cls_W1, cls_b1, cls_W2, WSf);
    tgn_mfma<<<GRID, BLK, 0, stream>>>(src_ids, dst_ids, edge_feat, delta_t,
                                       memory, cls_b2, WSf, winner,
                                       probs, outmem, E, N, ngrp);
}